// Round 1
// baseline (543.293 us; speedup 1.0000x reference)
//
#include <hip/hip_runtime.h>

#define B_ 32
#define N_ 4096
#define D_ 512
#define K_ 64

// ---------------------------------------------------------------------------
// Kernel A: logits = x @ clusters, BN(eval), softmax -> assignment; a_sum.
// Block: 64 rows x 64 cols, 256 threads, 4x4 register tile.
// ---------------------------------------------------------------------------
__global__ __launch_bounds__(256) void k_assign(
    const float* __restrict__ x, const float* __restrict__ clusters,
    const float* __restrict__ bnw, const float* __restrict__ bnb,
    const float* __restrict__ rm, const float* __restrict__ rv,
    float* __restrict__ asg, float* __restrict__ a_sum)
{
    const int tid = threadIdx.x;
    const int tx = tid & 15, ty = tid >> 4;
    const int r0 = blockIdx.x * 64;          // 64 rows per block, one batch
    const int b  = r0 >> 12;                 // N_=4096 rows per batch

    __shared__ __align__(16) float xs[32][68];   // [kk][row], padded
    __shared__ __align__(16) float cs[32][68];   // [kk][col], padded
    __shared__ float red[16][64];

    float acc[4][4] = {};

    for (int k0 = 0; k0 < D_; k0 += 32) {
        // x tile, transposed into LDS: xs[kk][row] = x[r0+row][k0+kk]
        #pragma unroll
        for (int l = 0; l < 2; ++l) {
            int idx = tid + (l << 8);        // 0..511 float4s
            int row = idx >> 3;              // 64 rows
            int kk4 = (idx & 7) << 2;        // 0..28
            const float4 v = *(const float4*)&x[(size_t)(r0 + row) * D_ + k0 + kk4];
            xs[kk4 + 0][row] = v.x;
            xs[kk4 + 1][row] = v.y;
            xs[kk4 + 2][row] = v.z;
            xs[kk4 + 3][row] = v.w;
        }
        // clusters tile: cs[kk][c] = clusters[k0+kk][c]
        #pragma unroll
        for (int l = 0; l < 2; ++l) {
            int idx = tid + (l << 8);
            int kk  = idx >> 4;
            int c4  = (idx & 15) << 2;
            *(float4*)&cs[kk][c4] = *(const float4*)&clusters[(size_t)(k0 + kk) * K_ + c4];
        }
        __syncthreads();
        #pragma unroll
        for (int kk = 0; kk < 32; ++kk) {
            const float4 xv = *(const float4*)&xs[kk][ty << 2];
            const float4 cv = *(const float4*)&cs[kk][tx << 2];
            const float xa[4] = {xv.x, xv.y, xv.z, xv.w};
            const float ca[4] = {cv.x, cv.y, cv.z, cv.w};
            #pragma unroll
            for (int i = 0; i < 4; ++i)
                #pragma unroll
                for (int j = 0; j < 4; ++j)
                    acc[i][j] = fmaf(xa[i], ca[j], acc[i][j]);
        }
        __syncthreads();
    }

    // BatchNorm (eval): l' = l*alpha + beta, alpha = w/sqrt(rv+eps), beta = b - rm*alpha
    const float4 w4 = *(const float4*)&bnw[tx << 2];
    const float4 b4 = *(const float4*)&bnb[tx << 2];
    const float4 m4 = *(const float4*)&rm[tx << 2];
    const float4 v4 = *(const float4*)&rv[tx << 2];
    const float wa[4] = {w4.x, w4.y, w4.z, w4.w};
    const float ba[4] = {b4.x, b4.y, b4.z, b4.w};
    const float ma[4] = {m4.x, m4.y, m4.z, m4.w};
    const float va[4] = {v4.x, v4.y, v4.z, v4.w};
    float alpha[4], beta[4];
    #pragma unroll
    for (int j = 0; j < 4; ++j) {
        alpha[j] = wa[j] * rsqrtf(va[j] + 1e-5f);
        beta[j]  = ba[j] - ma[j] * alpha[j];
    }

    // softmax over 64 cols: each row lives in 16 consecutive lanes (same ty)
    float rs[4] = {0.f, 0.f, 0.f, 0.f};
    #pragma unroll
    for (int i = 0; i < 4; ++i) {
        float lg[4];
        #pragma unroll
        for (int j = 0; j < 4; ++j) lg[j] = fmaf(acc[i][j], alpha[j], beta[j]);
        float mx = fmaxf(fmaxf(lg[0], lg[1]), fmaxf(lg[2], lg[3]));
        #pragma unroll
        for (int msk = 1; msk <= 8; msk <<= 1) mx = fmaxf(mx, __shfl_xor(mx, msk));
        float e[4];
        float s = 0.f;
        #pragma unroll
        for (int j = 0; j < 4; ++j) { e[j] = __expf(lg[j] - mx); s += e[j]; }
        #pragma unroll
        for (int msk = 1; msk <= 8; msk <<= 1) s += __shfl_xor(s, msk);
        const float invs = 1.0f / s;
        float4 o;
        o.x = e[0] * invs; o.y = e[1] * invs; o.z = e[2] * invs; o.w = e[3] * invs;
        const int row = (ty << 2) + i;
        *(float4*)&asg[(size_t)(r0 + row) * K_ + (tx << 2)] = o;
        rs[0] += o.x; rs[1] += o.y; rs[2] += o.z; rs[3] += o.w;
    }

    // block-level a_sum reduction
    *(float4*)&red[ty][tx << 2] = make_float4(rs[0], rs[1], rs[2], rs[3]);
    __syncthreads();
    if (tid < 64) {
        float s = 0.f;
        #pragma unroll
        for (int t2 = 0; t2 < 16; ++t2) s += red[t2][tid];
        atomicAdd(&a_sum[(b << 6) + tid], s);
    }
}

// ---------------------------------------------------------------------------
// Kernel B: part[s][b][d][k] = sum_{n in split s} x[b][n][d] * asg[b][n][k]
// Block: (n-split, d-tile, batch); 64 d x 64 k tile, 4x4 register tile.
// ---------------------------------------------------------------------------
__global__ __launch_bounds__(256) void k_vlad(
    const float* __restrict__ x, const float* __restrict__ asg,
    float* __restrict__ part)
{
    const int tid = threadIdx.x;
    const int tx = tid & 15, ty = tid >> 4;
    const int s  = blockIdx.x;   // 0..3 n-split
    const int dt = blockIdx.y;   // 0..7 d-tile
    const int b  = blockIdx.z;   // 0..31
    const int d0 = dt << 6;
    const int n0 = s << 10;

    __shared__ __align__(16) float xt[32][68];   // [nn][dd]
    __shared__ __align__(16) float at[32][68];   // [nn][k]

    float acc[4][4] = {};

    for (int nc = 0; nc < 32; ++nc) {
        const int nb = n0 + (nc << 5);
        #pragma unroll
        for (int l = 0; l < 2; ++l) {
            int idx = tid + (l << 8);
            int nn  = idx >> 4;
            int d4  = (idx & 15) << 2;
            *(float4*)&xt[nn][d4] =
                *(const float4*)&x[(size_t)(b * N_ + nb + nn) * D_ + d0 + d4];
        }
        #pragma unroll
        for (int l = 0; l < 2; ++l) {
            int idx = tid + (l << 8);
            int nn  = idx >> 4;
            int k4  = (idx & 15) << 2;
            *(float4*)&at[nn][k4] =
                *(const float4*)&asg[(size_t)(b * N_ + nb + nn) * K_ + k4];
        }
        __syncthreads();
        #pragma unroll
        for (int nn = 0; nn < 32; ++nn) {
            const float4 xv = *(const float4*)&xt[nn][ty << 2];
            const float4 av = *(const float4*)&at[nn][tx << 2];
            const float xa[4] = {xv.x, xv.y, xv.z, xv.w};
            const float aa[4] = {av.x, av.y, av.z, av.w};
            #pragma unroll
            for (int i = 0; i < 4; ++i)
                #pragma unroll
                for (int j = 0; j < 4; ++j)
                    acc[i][j] = fmaf(xa[i], aa[j], acc[i][j]);
        }
        __syncthreads();
    }

    #pragma unroll
    for (int i = 0; i < 4; ++i) {
        const size_t off =
            ((size_t)(s * B_ + b) * D_ + d0 + (ty << 2) + i) * K_ + (tx << 2);
        *(float4*)&part[off] = make_float4(acc[i][0], acc[i][1], acc[i][2], acc[i][3]);
    }
}

// ---------------------------------------------------------------------------
// Kernel C1: v = sum_s part - a_sum*clusters2 ; write to out; column ssq -> ssqk
// ---------------------------------------------------------------------------
__global__ __launch_bounds__(256) void k_final1(
    const float* __restrict__ part, const float* __restrict__ a_sum,
    const float* __restrict__ c2, float* __restrict__ out,
    float* __restrict__ ssqk)
{
    const int b  = blockIdx.x;
    const int dc = blockIdx.y;   // 0..3
    const int t  = threadIdx.x;
    const int k  = t & 63, g = t >> 6;
    __shared__ float sp[4][64];

    const float  ak = a_sum[(b << 6) + k];
    const size_t bo = (size_t)b * D_ * K_;
    const size_t PS = (size_t)B_ * D_ * K_;
    float ssq = 0.f;
    const int dlo = (dc << 7) + (g << 5);
    for (int d = dlo; d < dlo + 32; ++d) {
        const size_t off = ((size_t)d << 6) + k;
        float v = part[bo + off] + part[PS + bo + off]
                + part[2 * PS + bo + off] + part[3 * PS + bo + off];
        v = fmaf(-ak, c2[off], v);
        out[((size_t)b << 15) + off] = v;
        ssq = fmaf(v, v, ssq);
    }
    sp[g][k] = ssq;
    __syncthreads();
    if (t < 64)
        atomicAdd(&ssqk[(b << 6) + t], sp[0][t] + sp[1][t] + sp[2][t] + sp[3][t]);
}

// ---------------------------------------------------------------------------
// Kernel C2: scale by 1/max(||col||,eps) * 1/max(||row||,eps)
// ---------------------------------------------------------------------------
__global__ __launch_bounds__(256) void k_final2(
    const float* __restrict__ ssqk, float* __restrict__ out)
{
    const int b  = blockIdx.x;
    const int dc = blockIdx.y;
    const int t  = threadIdx.x;
    const int k  = t & 63, g = t >> 6;
    __shared__ float invk_s[64];
    __shared__ float invg_s;

    if (t < 64) {
        const float s   = ssqk[(b << 6) + t];
        const float inv = 1.0f / fmaxf(sqrtf(s), 1e-12f);
        invk_s[t] = inv;
        float gp = s * inv * inv;       // intra-normalized column ssq
        #pragma unroll
        for (int m = 1; m < 64; m <<= 1) gp += __shfl_xor(gp, m);
        if (t == 0) invg_s = 1.0f / fmaxf(sqrtf(gp), 1e-12f);
    }
    __syncthreads();
    const float scale = invk_s[k] * invg_s;
    const int dlo = (dc << 7) + (g << 5);
    for (int d = dlo; d < dlo + 32; ++d) {
        const size_t off = ((size_t)b << 15) + ((size_t)d << 6) + k;
        out[off] *= scale;
    }
}

// ---------------------------------------------------------------------------
extern "C" void kernel_launch(void* const* d_in, const int* in_sizes, int n_in,
                              void* d_out, int out_size, void* d_ws, size_t ws_size,
                              hipStream_t stream)
{
    const float* x    = (const float*)d_in[0];
    const float* clus = (const float*)d_in[1];
    const float* c2   = (const float*)d_in[2];
    const float* bnw  = (const float*)d_in[3];
    const float* bnb  = (const float*)d_in[4];
    const float* rm   = (const float*)d_in[5];
    const float* rv   = (const float*)d_in[6];
    float* out = (float*)d_out;

    float* asg   = (float*)d_ws;                         // B*N*K
    float* a_sum = asg + (size_t)B_ * N_ * K_;           // B*K
    float* ssqk  = a_sum + B_ * K_;                      // B*K
    float* part  = ssqk + B_ * K_;                       // 4*B*D*K

    hipMemsetAsync(a_sum, 0, 2 * B_ * K_ * sizeof(float), stream);

    k_assign<<<dim3(B_ * N_ / 64), 256, 0, stream>>>(x, clus, bnw, bnb, rm, rv, asg, a_sum);
    k_vlad<<<dim3(4, 8, B_), 256, 0, stream>>>(x, asg, part);
    k_final1<<<dim3(B_, 4), 256, 0, stream>>>(part, a_sum, c2, out, ssqk);
    k_final2<<<dim3(B_, 4), 256, 0, stream>>>(ssqk, out);
}

// Round 2
// 464.542 us; speedup vs baseline: 1.1695x; 1.1695x over previous
//
#include <hip/hip_runtime.h>
#include <stdint.h>

#define B_ 32
#define N_ 4096
#define D_ 512
#define K_ 64
#define M_ (B_ * N_)        // 131072 total tokens
#define NSPLIT 8            // n-splits for vlad partials

typedef float f32x4 __attribute__((ext_vector_type(4)));
typedef short bf16x8 __attribute__((ext_vector_type(8)));
typedef uint32_t u32;

union U8 { u32 u[4]; bf16x8 v; uint4 q4; };

// low16 = bf16_trunc(a), high16 = bf16_trunc(b)
__device__ __forceinline__ u32 pack_hi2(float a, float b) {
    return __builtin_amdgcn_perm(__float_as_uint(b), __float_as_uint(a), 0x07060302u);
}
// gather low16 halves of (p0,p1) -> u32
__device__ __forceinline__ u32 lo16s(u32 p0, u32 p1) {
    return __builtin_amdgcn_perm(p1, p0, 0x05040100u);
}
// gather high16 halves of (p0,p1) -> u32
__device__ __forceinline__ u32 hi16s(u32 p0, u32 p1) {
    return __builtin_amdgcn_perm(p1, p0, 0x07060302u);
}
__device__ __forceinline__ float trunc_hi(float f) {
    return __uint_as_float(__float_as_uint(f) & 0xffff0000u);
}

// ---------------------------------------------------------------------------
// Prep: clusters (D x K) -> frag-ordered bf16 hi/lo arrays.
// cfh/cfl[(t*4 + c)*64 + lane] elem j = B[t*32 + (lane>>4)*8 + j][c*16 + (lane&15)]
// ---------------------------------------------------------------------------
__global__ void k_prep(const float* __restrict__ clusters,
                       bf16x8* __restrict__ cfh, bf16x8* __restrict__ cfl)
{
    const int t = blockIdx.x;        // 0..15 k-chunk (32 wide)
    const int c = blockIdx.y;        // 0..3  col tile (16 wide)
    const int lane = threadIdx.x;    // 0..63
    const int q = lane >> 4, li = lane & 15;
    U8 h, l;
    #pragma unroll
    for (int j2 = 0; j2 < 4; ++j2) {
        float v0 = clusters[(t*32 + q*8 + 2*j2 + 0) * K_ + c*16 + li];
        float v1 = clusters[(t*32 + q*8 + 2*j2 + 1) * K_ + c*16 + li];
        float l0 = v0 - trunc_hi(v0), l1 = v1 - trunc_hi(v1);
        h.u[j2] = pack_hi2(v0, v1);
        l.u[j2] = pack_hi2(l0, l1);
    }
    cfh[(t*4 + c)*64 + lane] = h.v;
    cfl[(t*4 + c)*64 + lane] = l.v;
}

// ---------------------------------------------------------------------------
// Kernel A: logits = x @ clusters (bf16 hi/lo split MFMA), BN eval, softmax.
// Block: 128 rows, 4 waves x 32 rows. No LDS in main loop (A-frags direct
// from global; B-frags from frag-ordered L2-resident arrays).
// Epilogue: asgT[k][n] as packed (hi,lo) u32 pairs + a_sum atomics.
// ---------------------------------------------------------------------------
__global__ __launch_bounds__(256) void k_assign(
    const float* __restrict__ x,
    const bf16x8* __restrict__ cfh, const bf16x8* __restrict__ cfl,
    const float* __restrict__ bnw, const float* __restrict__ bnb,
    const float* __restrict__ rm, const float* __restrict__ rv,
    u32* __restrict__ asgT, float* __restrict__ a_sum)
{
    const int tid = threadIdx.x;
    const int w = tid >> 6, lane = tid & 63;
    const int q = lane >> 4, li = lane & 15;
    const int rbase = blockIdx.x * 128 + w * 32;

    __shared__ __align__(16) u32 asgT_lds[64][132];
    __shared__ float red[4][64];

    f32x4 acc[2][4];
    #pragma unroll
    for (int i = 0; i < 2; ++i)
        #pragma unroll
        for (int j = 0; j < 4; ++j) acc[i][j] = (f32x4){0.f, 0.f, 0.f, 0.f};

    for (int t = 0; t < 16; ++t) {
        bf16x8 bh[4], bl[4];
        #pragma unroll
        for (int c = 0; c < 4; ++c) {
            bh[c] = cfh[(t*4 + c)*64 + lane];
            bl[c] = cfl[(t*4 + c)*64 + lane];
        }
        #pragma unroll
        for (int mt = 0; mt < 2; ++mt) {
            const float* xp = x + (size_t)(rbase + mt*16 + li) * D_ + t*32 + q*8;
            float v[8];
            *(float4*)&v[0] = *(const float4*)xp;
            *(float4*)&v[4] = *(const float4*)(xp + 4);
            float lo[8];
            #pragma unroll
            for (int j = 0; j < 8; ++j) lo[j] = v[j] - trunc_hi(v[j]);
            U8 ah, al;
            #pragma unroll
            for (int j2 = 0; j2 < 4; ++j2) {
                ah.u[j2] = pack_hi2(v[2*j2], v[2*j2+1]);
                al.u[j2] = pack_hi2(lo[2*j2], lo[2*j2+1]);
            }
            #pragma unroll
            for (int c = 0; c < 4; ++c) {
                acc[mt][c] = __builtin_amdgcn_mfma_f32_16x16x32_bf16(ah.v, bh[c], acc[mt][c], 0, 0, 0);
                acc[mt][c] = __builtin_amdgcn_mfma_f32_16x16x32_bf16(ah.v, bl[c], acc[mt][c], 0, 0, 0);
                acc[mt][c] = __builtin_amdgcn_mfma_f32_16x16x32_bf16(al.v, bh[c], acc[mt][c], 0, 0, 0);
            }
        }
    }

    // BN(eval) coefficients per column
    float alpha[4], beta[4];
    #pragma unroll
    for (int c = 0; c < 4; ++c) {
        const int col = c*16 + li;
        const float a = bnw[col] * rsqrtf(rv[col] + 1e-5f);
        alpha[c] = a;
        beta[c]  = bnb[col] - rm[col] * a;
    }

    // softmax rows; write (hi,lo) pairs into LDS transpose tile
    float rs[4] = {0.f, 0.f, 0.f, 0.f};
    #pragma unroll
    for (int mt = 0; mt < 2; ++mt) {
        u32 pr[4][4];   // [reg][c]
        #pragma unroll
        for (int reg = 0; reg < 4; ++reg) {
            float lg[4];
            #pragma unroll
            for (int c = 0; c < 4; ++c) lg[c] = fmaf(acc[mt][c][reg], alpha[c], beta[c]);
            float mx = fmaxf(fmaxf(lg[0], lg[1]), fmaxf(lg[2], lg[3]));
            #pragma unroll
            for (int m = 1; m <= 8; m <<= 1) mx = fmaxf(mx, __shfl_xor(mx, m));
            float e[4], s = 0.f;
            #pragma unroll
            for (int c = 0; c < 4; ++c) { e[c] = __expf(lg[c] - mx); s += e[c]; }
            #pragma unroll
            for (int m = 1; m <= 8; m <<= 1) s += __shfl_xor(s, m);
            const float inv = 1.0f / s;
            #pragma unroll
            for (int c = 0; c < 4; ++c) {
                const float a = e[c] * inv;
                rs[c] += a;
                const float alo = a - trunc_hi(a);
                pr[reg][c] = pack_hi2(a, alo);
            }
        }
        #pragma unroll
        for (int c = 0; c < 4; ++c) {
            *(uint4*)&asgT_lds[c*16 + li][w*32 + mt*16 + q*4] =
                make_uint4(pr[0][c], pr[1][c], pr[2][c], pr[3][c]);
        }
    }

    // a_sum: reduce over q-groups, then across waves
    #pragma unroll
    for (int c = 0; c < 4; ++c) {
        rs[c] += __shfl_xor(rs[c], 16);
        rs[c] += __shfl_xor(rs[c], 32);
    }
    if (q == 0) {
        #pragma unroll
        for (int c = 0; c < 4; ++c) red[w][c*16 + li] = rs[c];
    }
    __syncthreads();
    if (tid < 64) {
        const float s = red[0][tid] + red[1][tid] + red[2][tid] + red[3][tid];
        atomicAdd(&a_sum[(blockIdx.x >> 5) * K_ + tid], s);
    }

    // coalesced asgT global write: [k][n-global]
    const size_t ncol0 = (size_t)blockIdx.x * 128;
    #pragma unroll
    for (int l = 0; l < 8; ++l) {
        const int ii = tid + 256*l;
        const int k = ii >> 5, seg = ii & 31;
        const uint4 vv = *(const uint4*)&asgT_lds[k][seg*4];
        *(uint4*)&asgT[(size_t)k * M_ + ncol0 + seg*4] = vv;
    }
}

// ---------------------------------------------------------------------------
// Kernel B: vladT[k][d] partials = asgT @ x  (hi/lo split MFMA).
// No LDS: A-frags (asg pairs) and B-frags (x, 8 row-strided dwords) direct
// from global. Grid (s=8, dblock=2, b=32); wave = 64k x 64d.
// ---------------------------------------------------------------------------
__global__ __launch_bounds__(256) void k_vlad(
    const float* __restrict__ x, const u32* __restrict__ asgT,
    float* __restrict__ part)
{
    const int tid = threadIdx.x;
    const int w = tid >> 6, lane = tid & 63;
    const int q = lane >> 4, li = lane & 15;
    const int s  = blockIdx.x;            // 0..7
    const int db = blockIdx.y;            // 0..1
    const int b  = blockIdx.z;            // 0..31
    const int d0 = db*256 + w*64;
    const int nbb = b * N_ + s * (N_ / NSPLIT);   // 512-token split

    f32x4 acc[4][4];
    #pragma unroll
    for (int i = 0; i < 4; ++i)
        #pragma unroll
        for (int j = 0; j < 4; ++j) acc[i][j] = (f32x4){0.f, 0.f, 0.f, 0.f};

    for (int ch = 0; ch < (N_ / NSPLIT) / 32; ++ch) {
        const int nb = ch*32 + q*8;
        // A frags: asg (hi,lo) pairs, contiguous in n
        bf16x8 ah[4], al[4];
        #pragma unroll
        for (int mt = 0; mt < 4; ++mt) {
            const u32* ap = asgT + (size_t)(mt*16 + li) * M_ + nbb + nb;
            u32 p[8];
            *(uint4*)&p[0] = *(const uint4*)ap;
            *(uint4*)&p[4] = *(const uint4*)(ap + 4);
            U8 uh, ul;
            #pragma unroll
            for (int j2 = 0; j2 < 4; ++j2) {
                uh.u[j2] = lo16s(p[2*j2], p[2*j2+1]);
                ul.u[j2] = hi16s(p[2*j2], p[2*j2+1]);
            }
            ah[mt] = uh.v; al[mt] = ul.v;
        }
        // B frags: x rows (strided), split in regs
        #pragma unroll
        for (int nt = 0; nt < 4; ++nt) {
            const float* xp = x + (size_t)(nbb + nb) * D_ + d0 + nt*16 + li;
            float v[8];
            #pragma unroll
            for (int j = 0; j < 8; ++j) v[j] = xp[(size_t)j * D_];
            float lo[8];
            #pragma unroll
            for (int j = 0; j < 8; ++j) lo[j] = v[j] - trunc_hi(v[j]);
            U8 bh, bl;
            #pragma unroll
            for (int j2 = 0; j2 < 4; ++j2) {
                bh.u[j2] = pack_hi2(v[2*j2], v[2*j2+1]);
                bl.u[j2] = pack_hi2(lo[2*j2], lo[2*j2+1]);
            }
            #pragma unroll
            for (int mt = 0; mt < 4; ++mt) {
                acc[mt][nt] = __builtin_amdgcn_mfma_f32_16x16x32_bf16(ah[mt], bh.v, acc[mt][nt], 0, 0, 0);
                acc[mt][nt] = __builtin_amdgcn_mfma_f32_16x16x32_bf16(ah[mt], bl.v, acc[mt][nt], 0, 0, 0);
                acc[mt][nt] = __builtin_amdgcn_mfma_f32_16x16x32_bf16(al[mt], bh.v, acc[mt][nt], 0, 0, 0);
            }
        }
    }

    // write partials: part[s][b][k][d]
    float* pp = part + ((size_t)s * B_ + b) * ((size_t)K_ * D_);
    #pragma unroll
    for (int mt = 0; mt < 4; ++mt)
        #pragma unroll
        for (int nt = 0; nt < 4; ++nt) {
            const int d = d0 + nt*16 + li;
            #pragma unroll
            for (int reg = 0; reg < 4; ++reg) {
                const int k = mt*16 + q*4 + reg;
                pp[(size_t)k * D_ + d] = acc[mt][nt][reg];
            }
        }
}

// ---------------------------------------------------------------------------
// C1: v[k][d] = sum_s part - a_sum*c2 ; write into part slice 0; ssq per k.
// ---------------------------------------------------------------------------
__global__ __launch_bounds__(256) void k_final1(
    const float* __restrict__ part_ro, const float* __restrict__ a_sum,
    const float* __restrict__ c2, float* __restrict__ part0,
    float* __restrict__ ssqk)
{
    const int b = blockIdx.x, dc = blockIdx.y;   // dc 0..7
    const int tid = threadIdx.x;
    const int k = tid >> 2, ds = tid & 3;
    const int d0 = dc*64 + ds*16;
    const float ak = a_sum[b*K_ + k];
    const size_t PS = (size_t)B_ * K_ * D_;
    const size_t base = ((size_t)b * K_ + k) * D_ + d0;
    float ssq = 0.f;
    #pragma unroll
    for (int i = 0; i < 4; ++i) {
        float4 v = *(const float4*)(part_ro + base + i*4);
        #pragma unroll
        for (int s = 1; s < NSPLIT; ++s) {
            const float4 p = *(const float4*)(part_ro + s*PS + base + i*4);
            v.x += p.x; v.y += p.y; v.z += p.z; v.w += p.w;
        }
        const int d = d0 + i*4;
        v.x = fmaf(-ak, c2[(d+0)*K_ + k], v.x);
        v.y = fmaf(-ak, c2[(d+1)*K_ + k], v.y);
        v.z = fmaf(-ak, c2[(d+2)*K_ + k], v.z);
        v.w = fmaf(-ak, c2[(d+3)*K_ + k], v.w);
        ssq = fmaf(v.x, v.x, fmaf(v.y, v.y, fmaf(v.z, v.z, fmaf(v.w, v.w, ssq))));
        *(float4*)(part0 + base + i*4) = v;
    }
    ssq += __shfl_xor(ssq, 1);
    ssq += __shfl_xor(ssq, 2);
    if (ds == 0) atomicAdd(&ssqk[b*K_ + k], ssq);
}

// ---------------------------------------------------------------------------
// C2: scale by intra/global inverse norms; transpose [k][d] -> out [d][k].
// ---------------------------------------------------------------------------
__global__ __launch_bounds__(256) void k_final2(
    const float* __restrict__ v0, const float* __restrict__ ssqk,
    float* __restrict__ out)
{
    const int b = blockIdx.x, dc = blockIdx.y;
    const int tid = threadIdx.x;
    __shared__ float T[64][65];
    __shared__ float invk[64];
    __shared__ float invg_s;

    if (tid < 64) {
        const float ss = ssqk[b*K_ + tid];
        const float inv = 1.0f / fmaxf(sqrtf(ss), 1e-12f);
        invk[tid] = inv;
        float gp = ss * inv * inv;
        #pragma unroll
        for (int m = 1; m < 64; m <<= 1) gp += __shfl_xor(gp, m);
        if (tid == 0) invg_s = 1.0f / fmaxf(sqrtf(gp), 1e-12f);
    }
    __syncthreads();

    const int k = tid >> 2, ds = tid & 3;
    const float sc = invk[k] * invg_s;
    const size_t base = ((size_t)b * K_ + k) * D_ + dc*64 + ds*16;
    #pragma unroll
    for (int i = 0; i < 4; ++i) {
        float4 v = *(const float4*)(v0 + base + i*4);
        const int dd = ds*16 + i*4;
        T[k][dd+0] = v.x * sc;
        T[k][dd+1] = v.y * sc;
        T[k][dd+2] = v.z * sc;
        T[k][dd+3] = v.w * sc;
    }
    __syncthreads();

    const int k2 = tid & 63, dl = tid >> 6;
    #pragma unroll
    for (int i = 0; i < 16; ++i) {
        const int dd = dl*16 + i;
        out[((size_t)b * D_ + dc*64 + dd) * K_ + k2] = T[k2][dd];
    }
}

// ---------------------------------------------------------------------------
extern "C" void kernel_launch(void* const* d_in, const int* in_sizes, int n_in,
                              void* d_out, int out_size, void* d_ws, size_t ws_size,
                              hipStream_t stream)
{
    const float* x    = (const float*)d_in[0];
    const float* clus = (const float*)d_in[1];
    const float* c2   = (const float*)d_in[2];
    const float* bnw  = (const float*)d_in[3];
    const float* bnb  = (const float*)d_in[4];
    const float* rm   = (const float*)d_in[5];
    const float* rv   = (const float*)d_in[6];
    float* out = (float*)d_out;

    u32*   asgT  = (u32*)d_ws;                                   // K_*M_ u32 = 33.5 MB
    float* part  = (float*)(asgT + (size_t)K_ * M_);             // NSPLIT*B_*K_*D_ = 33.5 MB
    float* a_sum = part + (size_t)NSPLIT * B_ * K_ * D_;         // B_*K_
    float* ssqk  = a_sum + B_ * K_;                              // B_*K_
    bf16x8* cfh  = (bf16x8*)(ssqk + B_ * K_);                    // 64 KB
    bf16x8* cfl  = cfh + 16*4*64;                                // 64 KB

    hipMemsetAsync(a_sum, 0, 2 * B_ * K_ * sizeof(float), stream);

    k_prep<<<dim3(16, 4), 64, 0, stream>>>(clus, cfh, cfl);
    k_assign<<<dim3(M_ / 128), 256, 0, stream>>>(x, cfh, cfl, bnw, bnb, rm, rv, asgT, a_sum);
    k_vlad<<<dim3(NSPLIT, 2, B_), 256, 0, stream>>>(x, asgT, part);
    k_final1<<<dim3(B_, 8), 256, 0, stream>>>(part, a_sum, c2, part, ssqk);
    k_final2<<<dim3(B_, 8), 256, 0, stream>>>(part, ssqk, out);
}